// Round 1
// baseline (184.533 us; speedup 1.0000x reference)
//
#include <hip/hip_runtime.h>
#include <hip/hip_bf16.h>

#define BB 64
#define SS 2048
#define DD 512

typedef __attribute__((ext_vector_type(8))) short short8;            // 8 bf16 (A/B frag)
typedef __attribute__((ext_vector_type(8))) unsigned short ushort8;  // packing
typedef __attribute__((ext_vector_type(4))) float f32x4;             // C/D frag

__device__ __forceinline__ unsigned short f2bf(float f){
  union { float f; unsigned int u; } a; a.f = f;
  unsigned int r = a.u + 0x7fffu + ((a.u >> 16) & 1u);  // RNE
  return (unsigned short)(r >> 16);
}

__device__ __forceinline__ ushort8 pack8(float4 a, float4 b){
  ushort8 u;
  u[0]=f2bf(a.x); u[1]=f2bf(a.y); u[2]=f2bf(a.z); u[3]=f2bf(a.w);
  u[4]=f2bf(b.x); u[5]=f2bf(b.y); u[6]=f2bf(b.z); u[7]=f2bf(b.w);
  return u;
}

// ---- kernel 1: W1 fp32 -> bf16 (same [e][d] K-contiguous layout) ----
__global__ void cvt_w1_kernel(const float* __restrict__ W1, unsigned short* __restrict__ W1b){
  int i = blockIdx.x * blockDim.x + threadIdx.x;   // 65536 threads
  #pragma unroll
  for (int j = 0; j < 4; ++j){
    int idx = i + j * 65536;
    W1b[idx] = f2bf(W1[idx]);
  }
}

// ---- kernel 2: zero ctx region (atomics accumulate into it each launch) ----
__global__ void zero_ctx_kernel(float* __restrict__ ctx){
  int i = blockIdx.x * blockDim.x + threadIdx.x;   // 32768 threads, 1 elem each
  ctx[i] = 0.f;
}

// ---- kernel 3: fused scores = sum_e tanh(x@W1^T + b1)[.,e] * w2[e] ----
// BM=128 rows/wg, 8 waves split e 8-ways (64 cols each), K in 4 phases of 128,
// double-buffered LDS (2 x 32KB), XOR-swizzled, issue-early/write-late staging.
__launch_bounds__(512, 2)
__global__ void scores_kernel(const float* __restrict__ x,
                              const unsigned short* __restrict__ W1b,
                              const float* __restrict__ b1,
                              const float* __restrict__ w2,
                              float* __restrict__ scores){
  __shared__ __align__(16) unsigned short xs[2][128 * 128];  // 64KB total

  const int t    = threadIdx.x;
  const int lane = t & 63;
  const int wv   = t >> 6;            // wave id 0..7 -> e range wv*64..+64
  const int m0   = blockIdx.x * 128;

  f32x4 acc[8][4];
  #pragma unroll
  for (int mt = 0; mt < 8; ++mt)
    #pragma unroll
    for (int et = 0; et < 4; ++et)
      acc[mt][et] = (f32x4){0.f, 0.f, 0.f, 0.f};

  // staging map: chunk c = i*512 + t -> row = i*32 + (t>>4), colchunk = t&15 (8 floats)
  const int srow = t >> 4;            // 0..31
  const int scc  = t & 15;
  const int swz  = (srow & 7) << 4;   // row&7 is constant per thread across i

  // prologue: stage phase 0
  #pragma unroll
  for (int i = 0; i < 4; ++i){
    int row = i * 32 + srow;
    const float* src = x + (size_t)(m0 + row) * DD + scc * 8;
    float4 f0 = *(const float4*)src;
    float4 f1 = *(const float4*)(src + 4);
    *(ushort8*)((char*)&xs[0][0] + row * 256 + ((scc << 4) ^ swz)) = pack8(f0, f1);
  }
  __syncthreads();

  const int arow_off = lane & 15;     // row within 16-row m-tile / col within e-tile
  const int kgrp     = lane >> 4;     // 0..3 -> k sub-offset *8

  #pragma unroll
  for (int p = 0; p < 4; ++p){
    // issue next-phase global loads early (complete under the MFMA phase)
    float4 nf[8];
    if (p < 3){
      #pragma unroll
      for (int i = 0; i < 4; ++i){
        int row = i * 32 + srow;
        const float* src = x + (size_t)(m0 + row) * DD + (p + 1) * 128 + scc * 8;
        nf[2*i]   = *(const float4*)src;
        nf[2*i+1] = *(const float4*)(src + 4);
      }
    }
    const char* xb = (const char*)&xs[p & 1][0];
    #pragma unroll
    for (int k8 = 0; k8 < 4; ++k8){           // 4 k-steps of 32 per phase
      short8 a[8];
      #pragma unroll
      for (int mt = 0; mt < 8; ++mt){
        int row = mt * 16 + arow_off;
        a[mt] = *(const short8*)(xb + row * 256 + ((k8 * 64 + kgrp * 16) ^ ((row & 7) << 4)));
      }
      short8 bf[4];
      const int ks = p * 4 + k8;              // global k-step 0..15
      #pragma unroll
      for (int et = 0; et < 4; ++et){
        int e = (wv << 6) + (et << 4) + arow_off;
        bf[et] = *(const short8*)(W1b + (size_t)e * DD + ks * 32 + kgrp * 8);
      }
      #pragma unroll
      for (int mt = 0; mt < 8; ++mt)
        #pragma unroll
        for (int et = 0; et < 4; ++et)
          acc[mt][et] = __builtin_amdgcn_mfma_f32_16x16x32_bf16(a[mt], bf[et], acc[mt][et], 0, 0, 0);
    }
    // write staged regs -> other buffer (safe: its readers finished at prior barrier)
    if (p < 3){
      #pragma unroll
      for (int i = 0; i < 4; ++i){
        int row = i * 32 + srow;
        *(ushort8*)((char*)&xs[(p + 1) & 1][0] + row * 256 + ((scc << 4) ^ swz)) = pack8(nf[2*i], nf[2*i+1]);
      }
    }
    __syncthreads();
  }

  // epilogue: tanh + dot(w2), reduce over e
  float ps[8][4];
  #pragma unroll
  for (int mt = 0; mt < 8; ++mt)
    #pragma unroll
    for (int i = 0; i < 4; ++i) ps[mt][i] = 0.f;

  #pragma unroll
  for (int et = 0; et < 4; ++et){
    int e = (wv << 6) + (et << 4) + arow_off;   // C/D col = lane&15
    float b1v = b1[e];
    float w2v = w2[e];
    #pragma unroll
    for (int mt = 0; mt < 8; ++mt){
      #pragma unroll
      for (int i = 0; i < 4; ++i){
        float g = acc[mt][et][i] + b1v;
        g = fminf(15.f, fmaxf(-15.f, g));
        float ex = __expf(2.f * g);
        float th = 1.f - 2.f / (ex + 1.f);      // tanh(g)
        ps[mt][i] += th * w2v;
      }
    }
  }
  // reduce across the 16 lanes of each lane-group (e direction)
  #pragma unroll
  for (int mt = 0; mt < 8; ++mt)
    #pragma unroll
    for (int i = 0; i < 4; ++i){
      float v = ps[mt][i];
      v += __shfl_xor(v, 1);
      v += __shfl_xor(v, 2);
      v += __shfl_xor(v, 4);
      v += __shfl_xor(v, 8);
      ps[mt][i] = v;
    }
  // combine 8 waves' partials via LDS (alias buffer 0; all reads done at last barrier)
  float* psum = (float*)&xs[0][0];              // [8][128]
  if ((lane & 15) == 0){
    #pragma unroll
    for (int mt = 0; mt < 8; ++mt)
      #pragma unroll
      for (int i = 0; i < 4; ++i)
        psum[wv * 128 + mt * 16 + (lane >> 4) * 4 + i] = ps[mt][i];  // C/D row
  }
  __syncthreads();
  if (t < 128){
    float s = 0.f;
    #pragma unroll
    for (int w = 0; w < 8; ++w) s += psum[w * 128 + t];
    scores[m0 + t] = s;   // pre-softmax; b2 omitted (softmax-invariant)
  }
}

// ---- kernel 4: in-place row softmax over S=2048 ----
__global__ void softmax_kernel(float* __restrict__ wbuf){
  const int b = blockIdx.x;
  float* row = wbuf + (size_t)b * SS;
  const int t = threadIdx.x;                 // 256
  float v[8];
  #pragma unroll
  for (int i = 0; i < 8; ++i) v[i] = row[t + i * 256];
  float m = v[0];
  #pragma unroll
  for (int i = 1; i < 8; ++i) m = fmaxf(m, v[i]);
  #pragma unroll
  for (int msk = 32; msk >= 1; msk >>= 1) m = fmaxf(m, __shfl_xor(m, msk));
  __shared__ float redm[4], reds[4];
  if ((t & 63) == 0) redm[t >> 6] = m;
  __syncthreads();
  m = fmaxf(fmaxf(redm[0], redm[1]), fmaxf(redm[2], redm[3]));
  float s = 0.f;
  #pragma unroll
  for (int i = 0; i < 8; ++i){ v[i] = __expf(v[i] - m); s += v[i]; }
  #pragma unroll
  for (int msk = 32; msk >= 1; msk >>= 1) s += __shfl_xor(s, msk);
  if ((t & 63) == 0) reds[t >> 6] = s;
  __syncthreads();
  s = reds[0] + reds[1] + reds[2] + reds[3];
  float inv = 1.f / s;
  #pragma unroll
  for (int i = 0; i < 8; ++i) row[t + i * 256] = v[i] * inv;
}

// ---- kernel 5: ctx[b,d] = sum_s w[b,s] * x[b,s,d] ----
__global__ void ctx_kernel(const float* __restrict__ x, const float* __restrict__ wbuf,
                           float* __restrict__ ctx){
  const int blk = blockIdx.x;   // 64 b * 16 s-chunks
  const int b   = blk >> 4;
  const int sc  = blk & 15;
  const int t   = threadIdx.x;  // 256, each owns 2 consecutive d
  const float* xb = x + (size_t)b * SS * DD;
  float a0 = 0.f, a1 = 0.f;
  const int s0 = sc * 128;
  for (int s = s0; s < s0 + 128; ++s){
    float wv = wbuf[(size_t)b * SS + s];       // uniform -> scalar load
    float2 xv = *(const float2*)(xb + (size_t)s * DD + t * 2);
    a0 += wv * xv.x;
    a1 += wv * xv.y;
  }
  atomicAdd(&ctx[b * DD + t * 2],     a0);
  atomicAdd(&ctx[b * DD + t * 2 + 1], a1);
}

extern "C" void kernel_launch(void* const* d_in, const int* in_sizes, int n_in,
                              void* d_out, int out_size, void* d_ws, size_t ws_size,
                              hipStream_t stream){
  const float* x  = (const float*)d_in[0];
  const float* W1 = (const float*)d_in[1];
  const float* b1 = (const float*)d_in[2];
  const float* w2 = (const float*)d_in[3];
  // d_in[4] = b2: softmax-invariant, unused.

  float* ctx  = (float*)d_out;                   // [64*512]
  float* wout = (float*)d_out + BB * DD;         // [64*2048] scores -> weights (in place)
  unsigned short* W1b = (unsigned short*)d_ws;   // 512KB bf16 W1

  hipLaunchKernelGGL(cvt_w1_kernel,  dim3(256),  dim3(256), 0, stream, W1, W1b);
  hipLaunchKernelGGL(zero_ctx_kernel,dim3(128),  dim3(256), 0, stream, ctx);
  hipLaunchKernelGGL(scores_kernel,  dim3(1024), dim3(512), 0, stream, x, W1b, b1, w2, wout);
  hipLaunchKernelGGL(softmax_kernel, dim3(64),   dim3(256), 0, stream, wout);
  hipLaunchKernelGGL(ctx_kernel,     dim3(1024), dim3(256), 0, stream, x, wout, ctx);
}